// Round 1
// baseline (1157.129 us; speedup 1.0000x reference)
//
#include <hip/hip_runtime.h>
#include <math.h>

#define NSRC 50000
#define NDST 50000
#define NE   300000
#define SD   64
#define RD   32
#define HIDD 64
#define NHEAD 4
#define EDIM 16
#define HO   256
#define SLOPE 0.2f
#define LN_EPS 1e-5f

// out[n, j] = sum_k x[n*K+k] * W[j*K+k] + b[j]
// One output element per thread; W row cached in registers (loaded once per block).
template<int K, int OUT>
__global__ void lin_kernel(const float* __restrict__ x, const float* __restrict__ W,
                           const float* __restrict__ b, float* __restrict__ out, int N) {
    constexpr int ROWS = 256 / OUT;
    int t = threadIdx.x;
    int j = t % OUT;
    int rsub = t / OUT;
    float w[K];
#pragma unroll
    for (int k = 0; k < K; ++k) w[k] = W[j * K + k];
    float bj = b[j];
    for (int row0 = blockIdx.x * ROWS; row0 < N; row0 += gridDim.x * ROWS) {
        int row = row0 + rsub;
        if (row < N) {
            const float* xrow = x + (size_t)row * K;
            float acc = 0.f;
#pragma unroll
            for (int k = 0; k < K; ++k) acc += xrow[k] * w[k];
            out[(size_t)row * OUT + j] = acc + bj;
        }
    }
}

__device__ __forceinline__ unsigned int enc_f32(float x) {
    unsigned int bits = __float_as_uint(x);
    return (bits & 0x80000000u) ? ~bits : (bits | 0x80000000u);
}

// Per edge: xe on the fly (edge_rep[e,16] @ We^T), e = lrelu(xl[s]+xr[d]+xe),
// logits[e,h] = sum_o e[h,o]*att[h,o]; atomicMax encoded into menc[d,h].
__global__ void edge_logits_kernel(const float* __restrict__ xl, const float* __restrict__ xr,
                                   const float* __restrict__ erep, const int* __restrict__ src,
                                   const int* __restrict__ dst, const float* __restrict__ We,
                                   const float* __restrict__ att,
                                   float* __restrict__ logits, unsigned int* __restrict__ menc) {
    __shared__ float sWe[256][17];   // padded: stride 17 breaks bank conflicts
    __shared__ float satt[256];
    int t = threadIdx.x;
#pragma unroll
    for (int k = 0; k < 16; ++k) sWe[t][k] = We[t * 16 + k];
    satt[t] = att[t];
    __syncthreads();
    int lane = t & 63;
    int wid = t >> 6;
    for (int e = blockIdx.x * 4 + wid; e < NE; e += gridDim.x * 4) {
        int s = src[e], d = dst[e];
        float erv[16];
#pragma unroll
        for (int k = 0; k < 16; ++k) erv[k] = erep[(size_t)e * 16 + k];
        const float* xls = xl + (size_t)s * 256;
        const float* xrd = xr + (size_t)d * 256;
#pragma unroll
        for (int h = 0; h < 4; ++h) {
            int jj = h * 64 + lane;
            float xe = 0.f;
#pragma unroll
            for (int k = 0; k < 16; ++k) xe += erv[k] * sWe[jj][k];
            float v = xls[jj] + xrd[jj] + xe;
            v = (v >= 0.f) ? v : SLOPE * v;
            float p = v * satt[jj];
#pragma unroll
            for (int off = 32; off >= 1; off >>= 1) p += __shfl_xor(p, off, 64);
            if (lane == 0) {
                logits[(size_t)e * 4 + h] = p;
                atomicMax(&menc[(size_t)d * 4 + h], enc_f32(p));
            }
        }
    }
}

__global__ void decode_m_kernel(unsigned int* __restrict__ m) {
    int i = blockIdx.x * 256 + threadIdx.x;
    if (i < NDST * 4) {
        unsigned int e = m[i];
        float f;
        if (e == 0u) f = 0.0f;  // empty segment: -inf -> 0 per reference
        else f = __uint_as_float((e & 0x80000000u) ? (e ^ 0x80000000u) : ~e);
        ((float*)m)[i] = f;
    }
}

__global__ void ex_denom_kernel(float* __restrict__ logits, const float* __restrict__ m,
                                const int* __restrict__ dst, float* __restrict__ denom) {
    int i = blockIdx.x * 256 + threadIdx.x;
    if (i < NE * 4) {
        int e = i >> 2, h = i & 3;
        int d = dst[e];
        float ex = expf(logits[i] - m[d * 4 + h]);
        logits[i] = ex;   // overwrite logits with ex
        atomicAdd(&denom[d * 4 + h], ex);
    }
}

// hacc[d,o] += 0.25 * sum_h alpha[e,h] * xl[s, h*64+o]   (head-mean folded in)
__global__ void scatter_kernel(const float* __restrict__ xl, const float* __restrict__ exv,
                               const float* __restrict__ denom, const int* __restrict__ src,
                               const int* __restrict__ dst, float* __restrict__ hacc) {
    int t = threadIdx.x;
    int lane = t & 63, wid = t >> 6;
    for (int e = blockIdx.x * 4 + wid; e < NE; e += gridDim.x * 4) {
        int s = src[e], d = dst[e];
        float a0 = exv[(size_t)e * 4 + 0] / (denom[(size_t)d * 4 + 0] + 1e-16f);
        float a1 = exv[(size_t)e * 4 + 1] / (denom[(size_t)d * 4 + 1] + 1e-16f);
        float a2 = exv[(size_t)e * 4 + 2] / (denom[(size_t)d * 4 + 2] + 1e-16f);
        float a3 = exv[(size_t)e * 4 + 3] / (denom[(size_t)d * 4 + 3] + 1e-16f);
        const float* xls = xl + (size_t)s * 256;
        float val = 0.25f * (a0 * xls[lane] + a1 * xls[64 + lane] +
                             a2 * xls[128 + lane] + a3 * xls[192 + lane]);
        atomicAdd(&hacc[(size_t)d * 64 + lane], val);
    }
}

// One wave per node: v = hacc + bias + res; out = LayerNorm(v)*g + be
__global__ void finalize_kernel(const float* __restrict__ hacc, const float* __restrict__ bias,
                                const float* __restrict__ res, const float* __restrict__ g,
                                const float* __restrict__ be, float* __restrict__ out) {
    int t = threadIdx.x;
    int lane = t & 63, wid = t >> 6;
    int d = blockIdx.x * 4 + wid;
    if (d >= NDST) return;
    float v = hacc[(size_t)d * 64 + lane] + bias[lane] + res[(size_t)d * 64 + lane];
    float mean = v;
#pragma unroll
    for (int off = 32; off >= 1; off >>= 1) mean += __shfl_xor(mean, off, 64);
    mean *= (1.f / 64.f);
    float diff = v - mean;
    float var = diff * diff;
#pragma unroll
    for (int off = 32; off >= 1; off >>= 1) var += __shfl_xor(var, off, 64);
    var *= (1.f / 64.f);
    out[(size_t)d * 64 + lane] = diff * rsqrtf(var + LN_EPS) * g[lane] + be[lane];
}

extern "C" void kernel_launch(void* const* d_in, const int* in_sizes, int n_in,
                              void* d_out, int out_size, void* d_ws, size_t ws_size,
                              hipStream_t stream) {
    const float* send  = (const float*)d_in[0];
    const float* rec   = (const float*)d_in[1];
    const float* erep  = (const float*)d_in[2];
    const int*   eidx  = (const int*)d_in[3];
    const int*   srcI  = eidx;        // edge_index[0]
    const int*   dstI  = eidx + NE;   // edge_index[1]
    const float* Wl0   = (const float*)d_in[4];
    const float* bl0   = (const float*)d_in[5];
    const float* Wr0   = (const float*)d_in[6];
    const float* br0   = (const float*)d_in[7];
    const float* We0   = (const float*)d_in[8];
    const float* att0  = (const float*)d_in[9];
    const float* bias0 = (const float*)d_in[10];
    const float* g0    = (const float*)d_in[11];
    const float* be0   = (const float*)d_in[12];
    const float* Wl1   = (const float*)d_in[13];
    const float* bl1   = (const float*)d_in[14];
    const float* Wr1   = (const float*)d_in[15];
    const float* br1   = (const float*)d_in[16];
    const float* We1   = (const float*)d_in[17];
    const float* att1  = (const float*)d_in[18];
    const float* bias1 = (const float*)d_in[19];
    const float* g1    = (const float*)d_in[20];
    const float* be1   = (const float*)d_in[21];
    const float* resW  = (const float*)d_in[22];
    const float* resbv = (const float*)d_in[23];
    float* out = (float*)d_out;

    float* ws = (float*)d_ws;
    float* xl    = ws;  ws += (size_t)NSRC * 256;
    float* xr    = ws;  ws += (size_t)NDST * 256;
    float* exv   = ws;  ws += (size_t)NE * 4;
    float* mbuf  = ws;  ws += (size_t)NDST * 4;
    float* denom = ws;  ws += (size_t)NDST * 4;
    float* hacc  = ws;  ws += (size_t)NDST * 64;
    float* xdst  = ws;  ws += (size_t)NDST * 64;
    float* res0  = ws;  ws += (size_t)NDST * 64;

    // res0 = rec @ res_W^T + res_b
    lin_kernel<32, 64><<<2048, 256, 0, stream>>>(rec, resW, resbv, res0, NDST);

    // ---------------- layer 0 ----------------
    hipMemsetAsync(mbuf,  0, (size_t)NDST * 4 * sizeof(float), stream);
    hipMemsetAsync(denom, 0, (size_t)NDST * 4 * sizeof(float), stream);
    hipMemsetAsync(hacc,  0, (size_t)NDST * 64 * sizeof(float), stream);
    lin_kernel<64, 256><<<2048, 256, 0, stream>>>(send, Wl0, bl0, xl, NSRC);
    lin_kernel<32, 256><<<2048, 256, 0, stream>>>(rec,  Wr0, br0, xr, NDST);
    edge_logits_kernel<<<4096, 256, 0, stream>>>(xl, xr, erep, srcI, dstI, We0, att0,
                                                 exv, (unsigned int*)mbuf);
    decode_m_kernel<<<(NDST * 4 + 255) / 256, 256, 0, stream>>>((unsigned int*)mbuf);
    ex_denom_kernel<<<(NE * 4 + 255) / 256, 256, 0, stream>>>(exv, mbuf, dstI, denom);
    scatter_kernel<<<4096, 256, 0, stream>>>(xl, exv, denom, srcI, dstI, hacc);
    finalize_kernel<<<(NDST + 3) / 4, 256, 0, stream>>>(hacc, bias0, res0, g0, be0, xdst);

    // ---------------- layer 1 ----------------
    hipMemsetAsync(mbuf,  0, (size_t)NDST * 4 * sizeof(float), stream);
    hipMemsetAsync(denom, 0, (size_t)NDST * 4 * sizeof(float), stream);
    hipMemsetAsync(hacc,  0, (size_t)NDST * 64 * sizeof(float), stream);
    lin_kernel<64, 256><<<2048, 256, 0, stream>>>(send, Wl1, bl1, xl, NSRC);
    lin_kernel<64, 256><<<2048, 256, 0, stream>>>(xdst, Wr1, br1, xr, NDST);
    edge_logits_kernel<<<4096, 256, 0, stream>>>(xl, xr, erep, srcI, dstI, We1, att1,
                                                 exv, (unsigned int*)mbuf);
    decode_m_kernel<<<(NDST * 4 + 255) / 256, 256, 0, stream>>>((unsigned int*)mbuf);
    ex_denom_kernel<<<(NE * 4 + 255) / 256, 256, 0, stream>>>(exv, mbuf, dstI, denom);
    scatter_kernel<<<4096, 256, 0, stream>>>(xl, exv, denom, srcI, dstI, hacc);
    finalize_kernel<<<(NDST + 3) / 4, 256, 0, stream>>>(hacc, bias1, xdst, g1, be1, out);
}